// Round 1
// baseline (80.344 us; speedup 1.0000x reference)
//
#include <hip/hip_runtime.h>
#include <hip/hip_bf16.h>

// out[e] = concat(h[i0], h[i1]) @ W + b, h = logmap0(x)
// Rewritten: y[n][0:4] = h[n]·W[0:128,:], y[n][4:8] = h[n]·W[128:256,:]
//            out[e][c] = y[i0][c] + y[i1][4+c] + b[c]

#define DIM 128

// One 64-lane wave per node. Lane l owns dims {l, l+64} of x and rows
// {l, l+64, 128+l, 192+l} of W (kept in registers).
__global__ void node_proj_kernel(const float* __restrict__ x,
                                 const float* __restrict__ W,
                                 float* __restrict__ y,
                                 int n_nodes) {
    const int lane = threadIdx.x & 63;
    const int waves_per_block = blockDim.x >> 6;
    const int wave_id = blockIdx.x * waves_per_block + (threadIdx.x >> 6);
    const int n_waves = gridDim.x * waves_per_block;

    // Per-lane W rows (row-major [256][4]) -> 16 floats in registers.
    const float4 w0a = *(const float4*)(W + (size_t)(lane)       * 4);
    const float4 w0b = *(const float4*)(W + (size_t)(lane + 64)  * 4);
    const float4 w1a = *(const float4*)(W + (size_t)(lane + 128) * 4);
    const float4 w1b = *(const float4*)(W + (size_t)(lane + 192) * 4);

    for (int n = wave_id; n < n_nodes; n += n_waves) {
        const float x0 = x[(size_t)n * DIM + lane];
        const float x1 = x[(size_t)n * DIM + 64 + lane];

        float acc[9];
        acc[0] = x0 * x0 + x1 * x1;              // sumsq partial
        acc[1] = x0 * w0a.x + x1 * w0b.x;        // dot with W[:,c], first half
        acc[2] = x0 * w0a.y + x1 * w0b.y;
        acc[3] = x0 * w0a.z + x1 * w0b.z;
        acc[4] = x0 * w0a.w + x1 * w0b.w;
        acc[5] = x0 * w1a.x + x1 * w1b.x;        // dot with W[128+:,c]
        acc[6] = x0 * w1a.y + x1 * w1b.y;
        acc[7] = x0 * w1a.z + x1 * w1b.z;
        acc[8] = x0 * w1a.w + x1 * w1b.w;

#pragma unroll
        for (int i = 0; i < 9; ++i) {
#pragma unroll
            for (int m = 32; m >= 1; m >>= 1)
                acc[i] += __shfl_xor(acc[i], m, 64);
        }

        if (lane == 0) {
            float norm = sqrtf(acc[0]);
            norm = fmaxf(norm, 1e-15f);                 // MIN_NORM clamp
            const float a = fminf(norm, 1.0f - 1e-6f);  // clip (norm >= 0)
            // artanh(a) = 0.5*log1p(2a/(1-a)) — accurate for a -> 0 and a -> 1
            const float art = 0.5f * log1pf(2.0f * a / (1.0f - a));
            const float scale = art / norm;
            float4 o0 = {acc[1] * scale, acc[2] * scale, acc[3] * scale, acc[4] * scale};
            float4 o1 = {acc[5] * scale, acc[6] * scale, acc[7] * scale, acc[8] * scale};
            *(float4*)(y + (size_t)n * 8)     = o0;
            *(float4*)(y + (size_t)n * 8 + 4) = o1;
        }
    }
}

__global__ void edge_kernel(const int* __restrict__ idx,
                            const float* __restrict__ y,
                            const float* __restrict__ b,
                            float* __restrict__ out,
                            int n_edges) {
    const int e = blockIdx.x * blockDim.x + threadIdx.x;
    if (e >= n_edges) return;
    const int2 ii = ((const int2*)idx)[e];
    const float4 a0 = *(const float4*)(y + (size_t)ii.x * 8);
    const float4 a1 = *(const float4*)(y + (size_t)ii.y * 8 + 4);
    float4 o;
    o.x = a0.x + a1.x + b[0];
    o.y = a0.y + a1.y + b[1];
    o.z = a0.z + a1.z + b[2];
    o.w = a0.w + a1.w + b[3];
    *(float4*)(out + (size_t)e * 4) = o;
}

extern "C" void kernel_launch(void* const* d_in, const int* in_sizes, int n_in,
                              void* d_out, int out_size, void* d_ws, size_t ws_size,
                              hipStream_t stream) {
    const float* x   = (const float*)d_in[0];
    const int*   idx = (const int*)d_in[1];
    const float* W   = (const float*)d_in[2];
    const float* b   = (const float*)d_in[3];
    float* out = (float*)d_out;

    const int n_nodes = in_sizes[0] / DIM;
    const int n_edges = in_sizes[1] / 2;

    float* y = (float*)d_ws;  // n_nodes * 8 floats = 3.2 MB

    // Kernel 1: 256 threads = 4 waves/block, grid-stride over nodes.
    const int waves_needed = n_nodes;            // 1 node per wave-iteration
    int blocks1 = (waves_needed + 3) / 4;
    if (blocks1 > 2048) blocks1 = 2048;
    node_proj_kernel<<<blocks1, 256, 0, stream>>>(x, W, y, n_nodes);

    // Kernel 2: 1 thread per edge.
    const int blocks2 = (n_edges + 255) / 256;
    edge_kernel<<<blocks2, 256, 0, stream>>>(idx, y, b, out, n_edges);
}

// Round 2
// 31.975 us; speedup vs baseline: 2.5128x; 2.5128x over previous
//
#include <hip/hip_runtime.h>
#include <hip/hip_bf16.h>

// out[e] = concat(h[i0], h[i1]) @ W + b, h = logmap0(x)
// Rewritten: y[n][0:4] = h[n]·W[0:128,:] + b   (b folded here)
//            y[n][4:8] = h[n]·W[128:256,:]
//            out[e][c] = y[i0][c] + y[i1][4+c]

#define DIM 128

// 4 lanes per node, 2 nodes per lane-group per iteration (32 nodes/wave).
// Lane li of a group owns dims {j*16 + li*4 + k : j=0..7, k=0..3}.
// W packed in LDS: Wp[d] = {W[d][0:4], W[d+128][0:4]} at float-offset
// d*8 + (d>>2)*4 (skew every 4 rows -> conflict-free 4-address reads).
__global__ __launch_bounds__(256) void node_proj_kernel(
    const float* __restrict__ x, const float* __restrict__ W,
    const float* __restrict__ b, float* __restrict__ y, int n_nodes)
{
    __shared__ float wp[1152];
    const int t = threadIdx.x;
    {
        const int r = t & 127, h = t >> 7;            // row, half
        const float4 wv = ((const float4*)W)[t];      // W[256][4], row t
        *(float4*)(wp + r * 8 + (r >> 2) * 4 + h * 4) = wv;
    }
    __syncthreads();

    const int lane = t & 63;
    const int li   = lane & 3;
    const int gid  = lane >> 2;
    const int wid  = blockIdx.x * (blockDim.x >> 6) + (t >> 6);
    const int n0   = wid * 32 + gid * 2;
    if (n0 >= n_nodes) return;
    const bool has1 = (n0 + 1) < n_nodes;
    const int  n1   = has1 ? (n0 + 1) : n0;

    const float* xp0 = x + (size_t)n0 * DIM + li * 4;
    const float* xp1 = x + (size_t)n1 * DIM + li * 4;
    const float* wl  = wp + li * 36;   // f(li*4) = li*32 + li*4

    float acc0[9], acc1[9];
#pragma unroll
    for (int i = 0; i < 9; ++i) { acc0[i] = 0.f; acc1[i] = 0.f; }

#pragma unroll
    for (int j = 0; j < 8; ++j) {
        const float4 a4 = *(const float4*)(xp0 + j * 16);
        const float4 b4 = *(const float4*)(xp1 + j * 16);
        const float av[4] = {a4.x, a4.y, a4.z, a4.w};
        const float bv[4] = {b4.x, b4.y, b4.z, b4.w};
#pragma unroll
        for (int k = 0; k < 4; ++k) {
            // d = j*16 + li*4 + k ; float-offset f(d) = li*36 + j*144 + k*8
            const float4 wa = *(const float4*)(wl + j * 144 + k * 8);
            const float4 wb = *(const float4*)(wl + j * 144 + k * 8 + 4);
            const float a = av[k], bb = bv[k];
            acc0[0] += a * a;       acc1[0] += bb * bb;
            acc0[1] += a * wa.x;    acc1[1] += bb * wa.x;
            acc0[2] += a * wa.y;    acc1[2] += bb * wa.y;
            acc0[3] += a * wa.z;    acc1[3] += bb * wa.z;
            acc0[4] += a * wa.w;    acc1[4] += bb * wa.w;
            acc0[5] += a * wb.x;    acc1[5] += bb * wb.x;
            acc0[6] += a * wb.y;    acc1[6] += bb * wb.y;
            acc0[7] += a * wb.z;    acc1[7] += bb * wb.z;
            acc0[8] += a * wb.w;    acc1[8] += bb * wb.w;
        }
    }

    // 2-step butterfly within each 4-lane group.
#pragma unroll
    for (int i = 0; i < 9; ++i) {
        acc0[i] += __shfl_xor(acc0[i], 1, 64);
        acc0[i] += __shfl_xor(acc0[i], 2, 64);
        acc1[i] += __shfl_xor(acc1[i], 1, 64);
        acc1[i] += __shfl_xor(acc1[i], 2, 64);
    }

    // li=0 -> y[n0][0:4], li=1 -> y[n0][4:8], li=2 -> y[n1][0:4], li=3 -> y[n1][4:8]
    const bool second = (li & 1);
    const bool nodeB  = (li >= 2);

    const float sq = nodeB ? acc1[0] : acc0[0];
    const float w0 = second ? (nodeB ? acc1[5] : acc0[5]) : (nodeB ? acc1[1] : acc0[1]);
    const float w1 = second ? (nodeB ? acc1[6] : acc0[6]) : (nodeB ? acc1[2] : acc0[2]);
    const float w2 = second ? (nodeB ? acc1[7] : acc0[7]) : (nodeB ? acc1[3] : acc0[3]);
    const float w3 = second ? (nodeB ? acc1[8] : acc0[8]) : (nodeB ? acc1[4] : acc0[4]);

    float norm = fmaxf(sqrtf(sq), 1e-15f);               // MIN_NORM
    const float aa  = fminf(norm, 1.0f - 1e-6f);         // ATANH_EPS clip
    const float art = 0.5f * log1pf(2.0f * aa / (1.0f - aa));  // artanh
    const float scale = art / norm;

    const float4 bv4 = *(const float4*)b;
    float4 o;
    o.x = w0 * scale + (second ? 0.f : bv4.x);
    o.y = w1 * scale + (second ? 0.f : bv4.y);
    o.z = w2 * scale + (second ? 0.f : bv4.z);
    o.w = w3 * scale + (second ? 0.f : bv4.w);

    if (!(nodeB && !has1))
        *(float4*)(y + (size_t)n0 * 8 + li * 4) = o;
}

// 2 edges per thread for MLP; y table (3.2 MB) is L2-resident.
__global__ __launch_bounds__(256) void edge_kernel(
    const int* __restrict__ idx, const float* __restrict__ y,
    float* __restrict__ out, int n_edges)
{
    const int t  = blockIdx.x * blockDim.x + threadIdx.x;
    const int e0 = t * 2;
    if (e0 + 1 < n_edges) {
        const int4 ii = *(const int4*)(idx + (size_t)e0 * 2);
        const float4 a0 = *(const float4*)(y + (size_t)ii.x * 8);
        const float4 c0 = *(const float4*)(y + (size_t)ii.y * 8 + 4);
        const float4 a1 = *(const float4*)(y + (size_t)ii.z * 8);
        const float4 c1 = *(const float4*)(y + (size_t)ii.w * 8 + 4);
        float4 o0 = {a0.x + c0.x, a0.y + c0.y, a0.z + c0.z, a0.w + c0.w};
        float4 o1 = {a1.x + c1.x, a1.y + c1.y, a1.z + c1.z, a1.w + c1.w};
        ((float4*)out)[e0]     = o0;
        ((float4*)out)[e0 + 1] = o1;
    } else if (e0 < n_edges) {
        const int2 ii = ((const int2*)idx)[e0];
        const float4 a0 = *(const float4*)(y + (size_t)ii.x * 8);
        const float4 c0 = *(const float4*)(y + (size_t)ii.y * 8 + 4);
        float4 o0 = {a0.x + c0.x, a0.y + c0.y, a0.z + c0.z, a0.w + c0.w};
        ((float4*)out)[e0] = o0;
    }
}

extern "C" void kernel_launch(void* const* d_in, const int* in_sizes, int n_in,
                              void* d_out, int out_size, void* d_ws, size_t ws_size,
                              hipStream_t stream) {
    const float* x   = (const float*)d_in[0];
    const int*   idx = (const int*)d_in[1];
    const float* W   = (const float*)d_in[2];
    const float* b   = (const float*)d_in[3];
    float* out = (float*)d_out;

    const int n_nodes = in_sizes[0] / DIM;
    const int n_edges = in_sizes[1] / 2;

    float* y = (float*)d_ws;  // n_nodes * 8 floats = 3.2 MB

    // Kernel 1: 32 nodes per wave, 4 waves per block -> 128 nodes/block.
    const int blocks1 = (n_nodes + 127) / 128;
    node_proj_kernel<<<blocks1, 256, 0, stream>>>(x, W, b, y, n_nodes);

    // Kernel 2: 2 edges per thread.
    const int n_thr   = (n_edges + 1) / 2;
    const int blocks2 = (n_thr + 255) / 256;
    edge_kernel<<<blocks2, 256, 0, stream>>>(idx, y, out, n_edges);
}